// Round 1
// baseline (4168.284 us; speedup 1.0000x reference)
//
#include <hip/hip_runtime.h>
#include <math.h>

#define BB 64
#define CC 256
#define TT 32
#define HH 7
#define WW 7
#define HW 49
#define NN 1568          // T*H*W
#define KV 97
#define KN 300
#define DD 512
#define NTOK 392
#define TOTAL (BB*TT*HW) // 100352
#define CB 64            // c-chunk for conv staging

// ---------------- K0: transpose conv_w (d,c,k) -> wT (c,k,d) ----------------
__global__ void k_wt(const float* __restrict__ w, float* __restrict__ wT) {
    int idx = blockIdx.x * 256 + threadIdx.x;      // 1,179,648 total
    if (idx >= DD * CC * 9) return;
    int d = idx & (DD - 1);
    int r = idx >> 9;          // c*9 + k
    int k = r % 9;
    int c = r / 9;
    wT[idx] = w[(d * CC + c) * 9 + k];
}

// ---------------- K1: per-batch argmax of the two logit sets ----------------
__global__ void k_argmax(const float* __restrict__ pv, const float* __restrict__ pn,
                         int* __restrict__ clsv, int* __restrict__ clsn) {
    int b = threadIdx.x;
    if (b >= BB) return;
    {
        const float* r = pv + b * KV;
        float best = r[0]; int bi = 0;
        for (int k = 1; k < KV; ++k) { float v = r[k]; if (v > best) { best = v; bi = k; } }
        clsv[b] = bi;
    }
    {
        const float* r = pn + b * KN;
        float best = r[0]; int bi = 0;
        for (int k = 1; k < KN; ++k) { float v = r[k]; if (v > best) { best = v; bi = k; } }
        clsn[b] = bi;
    }
}

// ---------------- K2: row[b,n] = sum_c w_top[c] * x[b,c,n] (both heads) ----
__global__ void k_rows(const float* __restrict__ x, const float* __restrict__ wpv,
                       const float* __restrict__ wpn, const int* __restrict__ clsv,
                       const int* __restrict__ clsn,
                       float* __restrict__ rowv, float* __restrict__ rown_) {
    __shared__ float wv[CC], wn[CC];
    int b = blockIdx.y;
    int t = threadIdx.x;
    wv[t] = wpv[clsv[b] * CC + t];
    wn[t] = wpn[clsn[b] * CC + t];
    __syncthreads();
    int n = blockIdx.x * 256 + t;
    if (n >= NN) return;
    const float* xp = x + (size_t)b * CC * NN + n;
    float av = 0.f, an = 0.f;
    #pragma unroll 4
    for (int c = 0; c < CC; ++c) {
        float xv = xp[(size_t)c * NN];
        av = fmaf(wv[c], xv, av);
        an = fmaf(wn[c], xv, an);
    }
    rowv[b * NN + n] = av;
    rown_[b * NN + n] = an;
}

// ---------------- K3: minmax-normalize + top-392 mask + cam_gt --------------
__device__ __forceinline__ int binof(float v) {
    int i = (int)(v * 1024.f);
    return i < 0 ? 0 : (i > 1023 ? 1023 : i);
}

__device__ float block_red(float v, float* sbuf, int tid, bool ismax) {
    sbuf[tid] = v; __syncthreads();
    for (int s = 128; s > 0; s >>= 1) {
        if (tid < s) sbuf[tid] = ismax ? fmaxf(sbuf[tid], sbuf[tid + s])
                                       : fminf(sbuf[tid], sbuf[tid + s]);
        __syncthreads();
    }
    float r = sbuf[0]; __syncthreads();
    return r;
}

__global__ void k_cam(const float* __restrict__ rowv, const float* __restrict__ rown_,
                      float* __restrict__ cam) {
    __shared__ float rv[NN], rn[NN];
    __shared__ float sbuf[256];
    __shared__ int hv[1024], hn[1024];
    __shared__ int bstar_v, above_v, bstar_n, above_n;
    int b = blockIdx.x, tid = threadIdx.x;
    for (int n = tid; n < NN; n += 256) { rv[n] = rowv[b * NN + n]; rn[n] = rown_[b * NN + n]; }
    __syncthreads();
    float mnv = 1e30f, mxv = -1e30f, mnn = 1e30f, mxn = -1e30f;
    for (int n = tid; n < NN; n += 256) {
        float v = rv[n]; mnv = fminf(mnv, v); mxv = fmaxf(mxv, v);
        float u = rn[n]; mnn = fminf(mnn, u); mxn = fmaxf(mxn, u);
    }
    mnv = block_red(mnv, sbuf, tid, false);
    mxv = block_red(mxv, sbuf, tid, true);
    mnn = block_red(mnn, sbuf, tid, false);
    mxn = block_red(mxn, sbuf, tid, true);
    float iv = 1.f / (mxv - mnv), inn = 1.f / (mxn - mnn);
    for (int n = tid; n < NN; n += 256) {
        rv[n] = (rv[n] - mnv) * iv;
        rn[n] = (rn[n] - mnn) * inn;
    }
    for (int i = tid; i < 1024; i += 256) { hv[i] = 0; hn[i] = 0; }
    __syncthreads();
    for (int n = tid; n < NN; n += 256) {
        atomicAdd(&hv[binof(rv[n])], 1);
        atomicAdd(&hn[binof(rn[n])], 1);
    }
    __syncthreads();
    if (tid == 0) {           // suffix scan: find boundary bin for v
        int acc = 0, bb = 1023;
        while (acc + hv[bb] < NTOK) { acc += hv[bb]; --bb; }
        bstar_v = bb; above_v = acc;
    }
    if (tid == 64) {          // parallel (different wave): boundary bin for n
        int acc = 0, bb = 1023;
        while (acc + hn[bb] < NTOK) { acc += hn[bb]; --bb; }
        bstar_n = bb; above_n = acc;
    }
    __syncthreads();
    int bsv = bstar_v, abv = above_v, bsn = bstar_n, abn = above_n;
    for (int n = tid; n < NN; n += 256) {
        float v = rv[n]; int bv = binof(v); float mv = 0.f;
        if (bv > bsv) mv = v;
        else if (bv == bsv) {
            // exact tie-break inside boundary bin: rank by (value desc, index asc)
            int cnt = 0;
            for (int m = 0; m < NN; ++m) {
                float u = rv[m];
                if (binof(u) == bsv && (u > v || (u == v && m < n))) ++cnt;
            }
            if (cnt < NTOK - abv) mv = v;
        }
        float u0 = rn[n]; int bu = binof(u0); float mu = 0.f;
        if (bu > bsn) mu = u0;
        else if (bu == bsn) {
            int cnt = 0;
            for (int m = 0; m < NN; ++m) {
                float u = rn[m];
                if (binof(u) == bsn && (u > u0 || (u == u0 && m < n))) ++cnt;
            }
            if (cnt < NTOK - abn) mu = u0;
        }
        cam[b * NN + n] = fmaxf(mv, mu);
    }
}

// ---------------- K4: fused conv3x3 + relu + score + BCE partial ------------
__global__ __launch_bounds__(448) void k_conv(
        const float* __restrict__ x, const float* __restrict__ wT,
        const float* __restrict__ convb, const float* __restrict__ scorew,
        const float* __restrict__ scoreb, const float* __restrict__ cam,
        float* __restrict__ partials) {
    __shared__ float xs[CB * 9 * 12];   // padded frame chunk [c][row 9][col 12]
    __shared__ float red[HW * 64];      // d-group reduction buffer
    int blk = blockIdx.x;
    int b = blk >> 5, t = blk & 31;
    int tid = threadIdx.x;
    int dg = tid & 63;                  // d-group: d = dg*8 .. dg*8+7
    int pg = tid >> 6;                  // output row h = pg (0..6)

    float acc[8][7];
    #pragma unroll
    for (int i = 0; i < 8; ++i)
        #pragma unroll
        for (int j = 0; j < 7; ++j) acc[i][j] = 0.f;

    // zero LDS once (borders stay zero across chunks)
    for (int i = tid; i < CB * 9 * 12; i += 448) xs[i] = 0.f;

    const float* xb = x + (size_t)b * CC * NN + (size_t)t * HW;
    for (int c0 = 0; c0 < CC; c0 += CB) {
        __syncthreads();
        for (int i = tid; i < CB * HW; i += 448) {
            int c = i / HW, q = i % HW;
            int h = q / WW, w = q % WW;
            xs[c * 108 + (h + 1) * 12 + (w + 1)] = xb[(size_t)(c0 + c) * NN + q];
        }
        __syncthreads();
        for (int c = 0; c < CB; ++c) {
            const float* wrow = wT + (size_t)(c0 + c) * 9 * DD + dg * 8;
            #pragma unroll
            for (int kh = 0; kh < 3; ++kh) {
                const float4* xr4 = (const float4*)(xs + c * 108 + (pg + kh) * 12);
                float4 xa = xr4[0], xbv = xr4[1], xcv = xr4[2];
                float xr[12] = {xa.x, xa.y, xa.z, xa.w, xbv.x, xbv.y, xbv.z, xbv.w,
                                xcv.x, xcv.y, xcv.z, xcv.w};
                #pragma unroll
                for (int kw = 0; kw < 3; ++kw) {
                    const float4* wp = (const float4*)(wrow + (kh * 3 + kw) * DD);
                    float4 w0 = wp[0], w1 = wp[1];
                    float wv[8] = {w0.x, w0.y, w0.z, w0.w, w1.x, w1.y, w1.z, w1.w};
                    #pragma unroll
                    for (int j = 0; j < 7; ++j) {
                        float xv = xr[j + kw];
                        #pragma unroll
                        for (int i = 0; i < 8; ++i)
                            acc[i][j] = fmaf(wv[i], xv, acc[i][j]);
                    }
                }
            }
        }
    }

    // epilogue: relu + score dot over this thread's 8 d's
    const float4* cb4 = (const float4*)(convb + dg * 8);
    const float4* sw4 = (const float4*)(scorew + dg * 8);
    float4 c0v = cb4[0], c1v = cb4[1], s0v = sw4[0], s1v = sw4[1];
    float cb[8] = {c0v.x, c0v.y, c0v.z, c0v.w, c1v.x, c1v.y, c1v.z, c1v.w};
    float sw[8] = {s0v.x, s0v.y, s0v.z, s0v.w, s1v.x, s1v.y, s1v.z, s1v.w};
    float part[7];
    #pragma unroll
    for (int j = 0; j < 7; ++j) {
        float s = 0.f;
        #pragma unroll
        for (int i = 0; i < 8; ++i) {
            float h1 = acc[i][j] + cb[i];
            h1 = h1 > 0.f ? h1 : 0.f;
            s = fmaf(sw[i], h1, s);
        }
        part[j] = s;
    }
    __syncthreads();
    #pragma unroll
    for (int j = 0; j < 7; ++j) red[(pg * 7 + j) * 64 + dg] = part[j];
    __syncthreads();
    if (tid < HW) {   // all in wave 0: lockstep makes read-then-write safe
        float s = 0.f;
        for (int g = 0; g < 64; ++g) s += red[tid * 64 + g];
        float l = s + scoreb[0];
        float y = cam[(size_t)b * NN + t * HW + tid];
        float bce = fmaxf(l, 0.f) - l * y + log1pf(expf(-fabsf(l)));
        red[tid] = bce;
    }
    __syncthreads();
    if (tid == 0) {
        float s = 0.f;
        for (int p = 0; p < HW; ++p) s += red[p];
        partials[blk] = s;
    }
}

// ---------------- K5: final mean ----------------
__global__ void k_final(const float* __restrict__ partials, float* __restrict__ out) {
    __shared__ float sbuf[256];
    int tid = threadIdx.x;
    float s = 0.f;
    for (int i = tid; i < BB * TT; i += 256) s += partials[i];
    sbuf[tid] = s; __syncthreads();
    for (int k = 128; k > 0; k >>= 1) {
        if (tid < k) sbuf[tid] += sbuf[tid + k];
        __syncthreads();
    }
    if (tid == 0) out[0] = sbuf[0] * (1.0f / (float)TOTAL);
}

extern "C" void kernel_launch(void* const* d_in, const int* in_sizes, int n_in,
                              void* d_out, int out_size, void* d_ws, size_t ws_size,
                              hipStream_t stream) {
    const float* x   = (const float*)d_in[0];
    const float* pv  = (const float*)d_in[1];
    const float* pn  = (const float*)d_in[2];
    const float* wpv = (const float*)d_in[3];
    const float* wpn = (const float*)d_in[4];
    const float* cw  = (const float*)d_in[5];
    const float* cb  = (const float*)d_in[6];
    const float* sw  = (const float*)d_in[7];
    const float* sb  = (const float*)d_in[8];

    float* ws    = (float*)d_ws;
    float* wT    = ws;                       // 1,179,648 floats
    float* rowv  = ws + 1179648;             // 100,352
    float* rown_ = rowv + 100352;            // 100,352
    float* cam   = rown_ + 100352;           // 100,352
    float* part  = cam + 100352;             // 2,048
    int*   clsv  = (int*)(part + 2048);      // 64
    int*   clsn  = clsv + 64;                // 64

    k_wt<<<4608, 256, 0, stream>>>(cw, wT);
    k_argmax<<<1, 64, 0, stream>>>(pv, pn, clsv, clsn);
    k_rows<<<dim3(7, BB), 256, 0, stream>>>(x, wpv, wpn, clsv, clsn, rowv, rown_);
    k_cam<<<BB, 256, 0, stream>>>(rowv, rown_, cam);
    k_conv<<<BB * TT, 448, 0, stream>>>(x, wT, cb, sw, sb, cam, part);
    k_final<<<1, 256, 0, stream>>>(part, (float*)d_out);
}

// Round 2
// 1045.139 us; speedup vs baseline: 3.9883x; 3.9883x over previous
//
#include <hip/hip_runtime.h>
#include <hip/hip_bf16.h>
#include <math.h>

#define BB 64
#define CC 256
#define TT 32
#define HH 7
#define WW 7
#define HW 49
#define NN 1568          // T*H*W
#define KV 97
#define KN 300
#define DD 512
#define NTOK 392
#define TOTAL (BB*TT*HW) // 100352

typedef float f32x4 __attribute__((ext_vector_type(4)));
typedef short bf16x8 __attribute__((ext_vector_type(8)));

#define GLDS(g, l) __builtin_amdgcn_global_load_lds(                          \
    (const __attribute__((address_space(1))) void*)(g),                       \
    (__attribute__((address_space(3))) void*)(l), 16, 0, 0)

// ---------------- K1: per-batch argmax of the two logit sets ----------------
__global__ void k_argmax(const float* __restrict__ pv, const float* __restrict__ pn,
                         int* __restrict__ clsv, int* __restrict__ clsn) {
    int b = threadIdx.x;
    if (b >= BB) return;
    {
        const float* r = pv + b * KV;
        float best = r[0]; int bi = 0;
        for (int k = 1; k < KV; ++k) { float v = r[k]; if (v > best) { best = v; bi = k; } }
        clsv[b] = bi;
    }
    {
        const float* r = pn + b * KN;
        float best = r[0]; int bi = 0;
        for (int k = 1; k < KN; ++k) { float v = r[k]; if (v > best) { best = v; bi = k; } }
        clsn[b] = bi;
    }
}

// ---------------- K2: build halo'd bf16 xp[b][t][9][9][c] + CAM rows -------
// One block per (b,t) frame. Stages the fp32 frame [c=256][q=49] in LDS
// (coalesced global read), writes the zero-padded bf16 transpose, and fuses
// the per-head CAM row dot products (saves a second full read of x).
__global__ __launch_bounds__(256) void k_xp(
        const float* __restrict__ x, __hip_bfloat16* __restrict__ xp,
        const float* __restrict__ wpv, const float* __restrict__ wpn,
        const int* __restrict__ clsv, const int* __restrict__ clsn,
        float* __restrict__ rowv, float* __restrict__ rown_) {
    __shared__ float xs[CC * HW];       // 50,176 B
    __shared__ float wvs[CC], wns[CC];
    int bt = blockIdx.x;                // 0..2047
    int b = bt >> 5, t = bt & 31;
    int tid = threadIdx.x;
    wvs[tid] = wpv[clsv[b] * CC + tid];
    wns[tid] = wpn[clsn[b] * CC + tid];
    const float* xb = x + ((size_t)b * CC * TT + t) * HW;  // + c*(TT*HW) + q
    for (int i = tid; i < CC * HW; i += 256) {
        int c = i / HW, q = i % HW;
        xs[i] = xb[(size_t)c * (TT * HW) + q];
    }
    __syncthreads();
    // padded transpose write: xp frame base bt*81*256, layout [p=hh*9+ww][c]
    __hip_bfloat16* xpb = xp + (size_t)bt * 81 * CC;
    for (int o = tid; o < 81 * CC; o += 256) {
        int p = o >> 8, c = o & 255;
        int hh = p / 9, ww = p % 9;
        float v = 0.f;
        if (hh >= 1 && hh <= 7 && ww >= 1 && ww <= 7)
            v = xs[c * HW + (hh - 1) * WW + (ww - 1)];
        xpb[o] = __float2bfloat16(v);
    }
    // fused CAM rows (fp32, exact): 98 threads, one (head, q) each
    if (tid < 2 * HW) {
        int head = tid >= HW;
        int q = head ? tid - HW : tid;
        const float* w = head ? wns : wvs;
        float s = 0.f;
        #pragma unroll 4
        for (int c = 0; c < CC; ++c) s = fmaf(w[c], xs[c * HW + q], s);
        (head ? rown_ : rowv)[bt * HW + q] = s;
    }
}

// ---------------- K3: weight transpose (d,c,kk) -> bf16 wb[kk][d][c] --------
__global__ void k_wb(const float* __restrict__ w, __hip_bfloat16* __restrict__ wb) {
    int o = blockIdx.x * 256 + threadIdx.x;       // 9*512*256 = 1,179,648
    if (o >= 9 * DD * CC) return;
    int kk = o / (DD * CC);
    int rem = o - kk * (DD * CC);
    int d = rem >> 8, c = rem & 255;
    wb[o] = __float2bfloat16(w[(d * CC + c) * 9 + kk]);
}

// ---------------- K4: minmax-normalize + top-392 mask + cam_gt --------------
__device__ __forceinline__ int binof(float v) {
    int i = (int)(v * 1024.f);
    return i < 0 ? 0 : (i > 1023 ? 1023 : i);
}

__device__ float block_red(float v, float* sbuf, int tid, bool ismax) {
    sbuf[tid] = v; __syncthreads();
    for (int s = 128; s > 0; s >>= 1) {
        if (tid < s) sbuf[tid] = ismax ? fmaxf(sbuf[tid], sbuf[tid + s])
                                       : fminf(sbuf[tid], sbuf[tid + s]);
        __syncthreads();
    }
    float r = sbuf[0]; __syncthreads();
    return r;
}

__global__ void k_cam(const float* __restrict__ rowv, const float* __restrict__ rown_,
                      float* __restrict__ cam) {
    __shared__ float rv[NN], rn[NN];
    __shared__ float sbuf[256];
    __shared__ int hv[1024], hn[1024];
    __shared__ int bstar_v, above_v, bstar_n, above_n;
    int b = blockIdx.x, tid = threadIdx.x;
    for (int n = tid; n < NN; n += 256) { rv[n] = rowv[b * NN + n]; rn[n] = rown_[b * NN + n]; }
    __syncthreads();
    float mnv = 1e30f, mxv = -1e30f, mnn = 1e30f, mxn = -1e30f;
    for (int n = tid; n < NN; n += 256) {
        float v = rv[n]; mnv = fminf(mnv, v); mxv = fmaxf(mxv, v);
        float u = rn[n]; mnn = fminf(mnn, u); mxn = fmaxf(mxn, u);
    }
    mnv = block_red(mnv, sbuf, tid, false);
    mxv = block_red(mxv, sbuf, tid, true);
    mnn = block_red(mnn, sbuf, tid, false);
    mxn = block_red(mxn, sbuf, tid, true);
    float iv = 1.f / (mxv - mnv), inn = 1.f / (mxn - mnn);
    for (int n = tid; n < NN; n += 256) {
        rv[n] = (rv[n] - mnv) * iv;
        rn[n] = (rn[n] - mnn) * inn;
    }
    for (int i = tid; i < 1024; i += 256) { hv[i] = 0; hn[i] = 0; }
    __syncthreads();
    for (int n = tid; n < NN; n += 256) {
        atomicAdd(&hv[binof(rv[n])], 1);
        atomicAdd(&hn[binof(rn[n])], 1);
    }
    __syncthreads();
    if (tid == 0) {
        int acc = 0, bb = 1023;
        while (acc + hv[bb] < NTOK) { acc += hv[bb]; --bb; }
        bstar_v = bb; above_v = acc;
    }
    if (tid == 64) {
        int acc = 0, bb = 1023;
        while (acc + hn[bb] < NTOK) { acc += hn[bb]; --bb; }
        bstar_n = bb; above_n = acc;
    }
    __syncthreads();
    int bsv = bstar_v, abv = above_v, bsn = bstar_n, abn = above_n;
    for (int n = tid; n < NN; n += 256) {
        float v = rv[n]; int bv = binof(v); float mv = 0.f;
        if (bv > bsv) mv = v;
        else if (bv == bsv) {
            int cnt = 0;
            for (int m = 0; m < NN; ++m) {
                float u = rv[m];
                if (binof(u) == bsv && (u > v || (u == v && m < n))) ++cnt;
            }
            if (cnt < NTOK - abv) mv = v;
        }
        float u0 = rn[n]; int bu = binof(u0); float mu = 0.f;
        if (bu > bsn) mu = u0;
        else if (bu == bsn) {
            int cnt = 0;
            for (int m = 0; m < NN; ++m) {
                float u = rn[m];
                if (binof(u) == bsn && (u > u0 || (u == u0 && m < n))) ++cnt;
            }
            if (cnt < NTOK - abn) mu = u0;
        }
        cam[b * NN + n] = fmaxf(mv, mu);
    }
}

// ---------------- K5: MFMA implicit-GEMM conv + fused relu/score ------------
// M=100352 (spatial), N=512 (d), K=2304 (c*9). m97 structure: 128x128 tile,
// BK=64, 4 waves of 4x4 16x16x32 fragments, global_load_lds width 16.
// A = halo'd xp rows (K-contiguous), B = wb[kk][d][c] rows (K-contiguous).
__global__ __launch_bounds__(256, 2) void k_gemm(
        const __hip_bfloat16* __restrict__ xp, const __hip_bfloat16* __restrict__ wb,
        const float* __restrict__ convb, const float* __restrict__ scorew,
        float* __restrict__ logits) {
    __shared__ char As[16384];   // [row 0..127][k' 0..63] bf16, 128 B rows
    __shared__ char Bs[16384];   // [d'  0..127][k' 0..63] bf16
    int tid = threadIdx.x;
    int n0 = blockIdx.x * 128;   // grid.x = 4  (adjacent blocks share A-tile in L2)
    int m0 = blockIdx.y * 128;   // grid.y = 784
    int lane = tid & 63, wv = tid >> 6;
    int wm = wv >> 1, wn = wv & 1;
    int ln = lane & 15, qd = lane >> 4;

    // per-thread staging coords: call j covers tile rows j*32 + tid/8, seg tid%8
    int bt_[4], hh_[4], ww_[4];
    const __hip_bfloat16* bptr[4];
    int rrow = tid >> 3, seg8 = (tid & 7) * 8;
    #pragma unroll
    for (int j = 0; j < 4; ++j) {
        int m = m0 + j * 32 + rrow;
        int bt = m / HW, q = m - bt * HW;
        bt_[j] = bt; hh_[j] = q / WW; ww_[j] = q - (q / WW) * WW;
        bptr[j] = wb + (size_t)(n0 + j * 32 + rrow) * 256 + seg8;
    }

    f32x4 acc[4][4];
    #pragma unroll
    for (int i = 0; i < 4; ++i)
        #pragma unroll
        for (int j = 0; j < 4; ++j) acc[i][j] = (f32x4){0.f, 0.f, 0.f, 0.f};

    for (int kk = 0; kk < 9; ++kk) {
        int kh = kk / 3, kw = kk - (kk / 3) * 3;
        const __hip_bfloat16* aptr[4];
        #pragma unroll
        for (int j = 0; j < 4; ++j)
            aptr[j] = xp + ((size_t)bt_[j] * 81 + (hh_[j] + kh) * 9 + (ww_[j] + kw)) * 256 + seg8;
        const size_t boff = (size_t)kk * (DD * 256);
        #pragma unroll
        for (int c0 = 0; c0 < 256; c0 += 64) {
            __syncthreads();
            #pragma unroll
            for (int j = 0; j < 4; ++j) {
                GLDS(aptr[j] + c0, As + j * 4096 + tid * 16);
                GLDS(bptr[j] + boff + c0, Bs + j * 4096 + tid * 16);
            }
            __syncthreads();
            #pragma unroll
            for (int k2 = 0; k2 < 2; ++k2) {
                bf16x8 af[4], bfr[4];
                #pragma unroll
                for (int i = 0; i < 4; ++i)
                    af[i] = *(const bf16x8*)(As + (wm * 64 + i * 16 + ln) * 128 + k2 * 64 + qd * 16);
                #pragma unroll
                for (int j = 0; j < 4; ++j)
                    bfr[j] = *(const bf16x8*)(Bs + (wn * 64 + j * 16 + ln) * 128 + k2 * 64 + qd * 16);
                #pragma unroll
                for (int i = 0; i < 4; ++i)
                    #pragma unroll
                    for (int j = 0; j < 4; ++j)
                        acc[i][j] = __builtin_amdgcn_mfma_f32_16x16x32_bf16(af[i], bfr[j], acc[i][j], 0, 0, 0);
            }
        }
    }

    // fused epilogue: relu + score partial dot over this block's 128 d's
    float swr[4], cbr[4];
    #pragma unroll
    for (int j = 0; j < 4; ++j) {
        int n = n0 + wn * 64 + j * 16 + ln;
        swr[j] = scorew[n];
        cbr[j] = convb[n];
    }
    #pragma unroll
    for (int i = 0; i < 4; ++i) {
        #pragma unroll
        for (int r = 0; r < 4; ++r) {
            float v = 0.f;
            #pragma unroll
            for (int j = 0; j < 4; ++j) {
                float h1 = acc[i][j][r] + cbr[j];
                h1 = h1 > 0.f ? h1 : 0.f;
                v = fmaf(swr[j], h1, v);
            }
            v += __shfl_xor(v, 1);
            v += __shfl_xor(v, 2);
            v += __shfl_xor(v, 4);
            v += __shfl_xor(v, 8);
            if (ln == 0)
                atomicAdd(&logits[m0 + wm * 64 + i * 16 + qd * 4 + r], v);
        }
    }
}

// ---------------- K6: BCE per element + block partials ----------------------
__global__ void k_bce(const float* __restrict__ logits, const float* __restrict__ cam,
                      const float* __restrict__ sb, float* __restrict__ part) {
    __shared__ float sbuf[256];
    int tid = threadIdx.x;
    int m = blockIdx.x * 256 + tid;
    float l = logits[m] + sb[0];
    float y = cam[m];
    float v = fmaxf(l, 0.f) - l * y + log1pf(expf(-fabsf(l)));
    sbuf[tid] = v; __syncthreads();
    for (int k = 128; k > 0; k >>= 1) {
        if (tid < k) sbuf[tid] += sbuf[tid + k];
        __syncthreads();
    }
    if (tid == 0) part[blockIdx.x] = sbuf[0];
}

// ---------------- K7: final mean --------------------------------------------
__global__ void k_final(const float* __restrict__ part, float* __restrict__ out) {
    __shared__ float sbuf[256];
    int tid = threadIdx.x;
    float s = 0.f;
    for (int i = tid; i < 392; i += 256) s += part[i];
    sbuf[tid] = s; __syncthreads();
    for (int k = 128; k > 0; k >>= 1) {
        if (tid < k) sbuf[tid] += sbuf[tid + k];
        __syncthreads();
    }
    if (tid == 0) out[0] = sbuf[0] * (1.0f / (float)TOTAL);
}

extern "C" void kernel_launch(void* const* d_in, const int* in_sizes, int n_in,
                              void* d_out, int out_size, void* d_ws, size_t ws_size,
                              hipStream_t stream) {
    const float* x   = (const float*)d_in[0];
    const float* pv  = (const float*)d_in[1];
    const float* pn  = (const float*)d_in[2];
    const float* wpv = (const float*)d_in[3];
    const float* wpn = (const float*)d_in[4];
    const float* cw  = (const float*)d_in[5];
    const float* cb  = (const float*)d_in[6];
    const float* sw  = (const float*)d_in[7];
    const float* sb  = (const float*)d_in[8];

    char* w8 = (char*)d_ws;
    __hip_bfloat16* xp  = (__hip_bfloat16*)w8;                  // 84,934,656 B
    __hip_bfloat16* wb  = (__hip_bfloat16*)(w8 + 84934656);     //  2,359,296 B
    float* logits = (float*)(w8 + 87293952);                    //    401,408 B
    float* rowv   = (float*)(w8 + 87695360);
    float* rown_  = (float*)(w8 + 88096768);
    float* cam    = (float*)(w8 + 88498176);
    float* part   = (float*)(w8 + 88899584);                    //      1,568 B
    int*   clsv   = (int*)(w8 + 88901152);
    int*   clsn   = clsv + 64;

    k_argmax<<<1, 64, 0, stream>>>(pv, pn, clsv, clsn);
    k_xp<<<BB * TT, 256, 0, stream>>>(x, xp, wpv, wpn, clsv, clsn, rowv, rown_);
    k_wb<<<4608, 256, 0, stream>>>(cw, wb);
    k_cam<<<BB, 256, 0, stream>>>(rowv, rown_, cam);
    hipMemsetAsync(logits, 0, TOTAL * sizeof(float), stream);
    k_gemm<<<dim3(4, 784), 256, 0, stream>>>(xp, wb, cb, sw, logits);
    k_bce<<<392, 256, 0, stream>>>(logits, cam, sb, part);
    k_final<<<1, 256, 0, stream>>>(part, (float*)d_out);
}

// Round 3
// 535.666 us; speedup vs baseline: 7.7815x; 1.9511x over previous
//
#include <hip/hip_runtime.h>
#include <hip/hip_bf16.h>
#include <math.h>

#define BB 64
#define CC 256
#define TT 32
#define HH 7
#define WW 7
#define HW 49
#define NN 1568          // T*H*W
#define KV 97
#define KN 300
#define DD 512
#define NTOK 392
#define TOTAL (BB*TT*HW) // 100352
#define BCAP 256         // boundary-bin compaction capacity per head

typedef float f32x4 __attribute__((ext_vector_type(4)));
typedef short bf16x8 __attribute__((ext_vector_type(8)));

#define GLDS(g, l) __builtin_amdgcn_global_load_lds(                          \
    (const __attribute__((address_space(1))) void*)(g),                       \
    (__attribute__((address_space(3))) void*)(l), 16, 0, 0)

// ---------------- K1: per-batch argmax of the two logit sets ----------------
__global__ void k_argmax(const float* __restrict__ pv, const float* __restrict__ pn,
                         int* __restrict__ clsv, int* __restrict__ clsn) {
    int b = threadIdx.x;
    if (b >= BB) return;
    {
        const float* r = pv + b * KV;
        float best = r[0]; int bi = 0;
        for (int k = 1; k < KV; ++k) { float v = r[k]; if (v > best) { best = v; bi = k; } }
        clsv[b] = bi;
    }
    {
        const float* r = pn + b * KN;
        float best = r[0]; int bi = 0;
        for (int k = 1; k < KN; ++k) { float v = r[k]; if (v > best) { best = v; bi = k; } }
        clsn[b] = bi;
    }
}

// ---------------- K2: build halo'd bf16 xp[b][t][9][9][c] + CAM rows -------
__global__ __launch_bounds__(256) void k_xp(
        const float* __restrict__ x, __hip_bfloat16* __restrict__ xp,
        const float* __restrict__ wpv, const float* __restrict__ wpn,
        const int* __restrict__ clsv, const int* __restrict__ clsn,
        float* __restrict__ rowv, float* __restrict__ rown_) {
    __shared__ float xs[CC * HW];       // 50,176 B
    __shared__ float wvs[CC], wns[CC];
    int bt = blockIdx.x;                // 0..2047
    int b = bt >> 5, t = bt & 31;
    int tid = threadIdx.x;
    wvs[tid] = wpv[clsv[b] * CC + tid];
    wns[tid] = wpn[clsn[b] * CC + tid];
    const float* xb = x + ((size_t)b * CC * TT + t) * HW;  // + c*(TT*HW) + q
    for (int i = tid; i < CC * HW; i += 256) {
        int c = i / HW, q = i % HW;
        xs[i] = xb[(size_t)c * (TT * HW) + q];
    }
    __syncthreads();
    __hip_bfloat16* xpb = xp + (size_t)bt * 81 * CC;
    for (int o = tid; o < 81 * CC; o += 256) {
        int p = o >> 8, c = o & 255;
        int hh = p / 9, ww = p % 9;
        float v = 0.f;
        if (hh >= 1 && hh <= 7 && ww >= 1 && ww <= 7)
            v = xs[c * HW + (hh - 1) * WW + (ww - 1)];
        xpb[o] = __float2bfloat16(v);
    }
    if (tid < 2 * HW) {
        int head = tid >= HW;
        int q = head ? tid - HW : tid;
        const float* w = head ? wns : wvs;
        float s = 0.f;
        #pragma unroll 4
        for (int c = 0; c < CC; ++c) s = fmaf(w[c], xs[c * HW + q], s);
        (head ? rown_ : rowv)[bt * HW + q] = s;
    }
}

// ---------------- K3: weight transpose (d,c,kk) -> bf16 wb[kk][d][c] --------
__global__ void k_wb(const float* __restrict__ w, __hip_bfloat16* __restrict__ wb) {
    int o = blockIdx.x * 256 + threadIdx.x;       // 9*512*256 = 1,179,648
    if (o >= 9 * DD * CC) return;
    int kk = o / (DD * CC);
    int rem = o - kk * (DD * CC);
    int d = rem >> 8, c = rem & 255;
    wb[o] = __float2bfloat16(w[(d * CC + c) * 9 + kk]);
}

// ---------------- K4: minmax-normalize + top-392 mask + cam_gt --------------
// Fully parallel selection: packed 2-head histogram, parallel suffix scan,
// compacted boundary-bin exact tie-break. No serial LDS-latency chains.
__device__ __forceinline__ int binof(float v) {
    int i = (int)(v * 1024.f);
    return i < 0 ? 0 : (i > 1023 ? 1023 : i);
}

__device__ float block_red(float v, float* sbuf, int tid, bool ismax) {
    sbuf[tid] = v; __syncthreads();
    for (int s = 128; s > 0; s >>= 1) {
        if (tid < s) sbuf[tid] = ismax ? fmaxf(sbuf[tid], sbuf[tid + s])
                                       : fminf(sbuf[tid], sbuf[tid + s]);
        __syncthreads();
    }
    float r = sbuf[0]; __syncthreads();
    return r;
}

__global__ __launch_bounds__(256) void k_cam(
        const float* __restrict__ rowv, const float* __restrict__ rown_,
        float* __restrict__ cam) {
    __shared__ float rv[NN], rn[NN];
    __shared__ float sbuf[256];
    __shared__ int h[1024];             // packed: lo16 = head v, hi16 = head n
    __shared__ int tsum[256];
    __shared__ float lval_v[BCAP], lval_n[BCAP];
    __shared__ int lidx_v[BCAP], lidx_n[BCAP];
    __shared__ int cntv, cntn, bstar_v, above_v, bstar_n, above_n;
    int b = blockIdx.x, tid = threadIdx.x;

    for (int n = tid; n < NN; n += 256) { rv[n] = rowv[b * NN + n]; rn[n] = rown_[b * NN + n]; }
    __syncthreads();
    float mnv = 1e30f, mxv = -1e30f, mnn = 1e30f, mxn = -1e30f;
    for (int n = tid; n < NN; n += 256) {
        float v = rv[n]; mnv = fminf(mnv, v); mxv = fmaxf(mxv, v);
        float u = rn[n]; mnn = fminf(mnn, u); mxn = fmaxf(mxn, u);
    }
    mnv = block_red(mnv, sbuf, tid, false);
    mxv = block_red(mxv, sbuf, tid, true);
    mnn = block_red(mnn, sbuf, tid, false);
    mxn = block_red(mxn, sbuf, tid, true);
    float iv = 1.f / (mxv - mnv), inn = 1.f / (mxn - mnn);

    // normalize in place; zero histogram + counters
    for (int n = tid; n < NN; n += 256) {
        rv[n] = (rv[n] - mnv) * iv;
        rn[n] = (rn[n] - mnn) * inn;
    }
    for (int i = tid; i < 1024; i += 256) h[i] = 0;
    if (tid == 0) { cntv = 0; cntn = 0; }
    __syncthreads();
    for (int n = tid; n < NN; n += 256) {
        atomicAdd(&h[binof(rv[n])], 1);
        atomicAdd(&h[binof(rn[n])], 1 << 16);
    }
    __syncthreads();

    // parallel suffix scan: thread t owns bins 4t..4t+3
    int h0 = h[4 * tid], h1 = h[4 * tid + 1], h2 = h[4 * tid + 2], h3 = h[4 * tid + 3];
    tsum[tid] = h0 + h1 + h2 + h3;      // packed fieldwise sum (<=1568 per field)
    __syncthreads();
    for (int off = 1; off < 256; off <<= 1) {
        int add = (tid + off < 256) ? tsum[tid + off] : 0;
        __syncthreads();
        tsum[tid] += add;
        __syncthreads();
    }
    // locate boundary per head: S(b) >= NTOK > S(b+1)
    {
        int scur = tsum[tid];           // packed S(4t)
        int hk[4] = {h0, h1, h2, h3};
        #pragma unroll
        for (int k = 0; k < 4; ++k) {
            int snext = scur - hk[k];   // fieldwise, borrow-free
            int sc = scur & 0xffff, nc = snext & 0xffff;
            int sh = scur >> 16, nh = snext >> 16;
            if (sc >= NTOK && nc < NTOK) { bstar_v = 4 * tid + k; above_v = nc; }
            if (sh >= NTOK && nh < NTOK) { bstar_n = 4 * tid + k; above_n = nh; }
            scur = snext;
        }
    }
    __syncthreads();
    int bsv = bstar_v, abv = above_v, bsn = bstar_n, abn = above_n;

    // zero below-boundary, compact boundary-bin elements
    for (int n = tid; n < NN; n += 256) {
        float v = rv[n]; int bv = binof(v);
        if (bv < bsv) rv[n] = 0.f;
        else if (bv == bsv) {
            int s = atomicAdd(&cntv, 1);
            if (s < BCAP) { lval_v[s] = v; lidx_v[s] = n; }
        }
        float u = rn[n]; int bu = binof(u);
        if (bu < bsn) rn[n] = 0.f;
        else if (bu == bsn) {
            int s = atomicAdd(&cntn, 1);
            if (s < BCAP) { lval_n[s] = u; lidx_n[s] = n; }
        }
    }
    __syncthreads();
    // exact rank among boundary elements (value desc, index asc)
    int Lv = cntv < BCAP ? cntv : BCAP;
    int Ln = cntn < BCAP ? cntn : BCAP;
    for (int i = tid; i < Lv; i += 256) {
        float vi = lval_v[i]; int ni = lidx_v[i]; int r = 0;
        for (int j = 0; j < Lv; ++j) {
            float vj = lval_v[j]; int nj = lidx_v[j];
            r += (vj > vi || (vj == vi && nj < ni)) ? 1 : 0;
        }
        rv[ni] = (r < NTOK - abv) ? vi : 0.f;
    }
    for (int i = tid; i < Ln; i += 256) {
        float vi = lval_n[i]; int ni = lidx_n[i]; int r = 0;
        for (int j = 0; j < Ln; ++j) {
            float vj = lval_n[j]; int nj = lidx_n[j];
            r += (vj > vi || (vj == vi && nj < ni)) ? 1 : 0;
        }
        rn[ni] = (r < NTOK - abn) ? vi : 0.f;
    }
    __syncthreads();
    for (int n = tid; n < NN; n += 256) cam[b * NN + n] = fmaxf(rv[n], rn[n]);
}

// ---------------- K5: MFMA implicit-GEMM conv + fused relu/score ------------
__global__ __launch_bounds__(256, 2) void k_gemm(
        const __hip_bfloat16* __restrict__ xp, const __hip_bfloat16* __restrict__ wb,
        const float* __restrict__ convb, const float* __restrict__ scorew,
        float* __restrict__ logits) {
    __shared__ char As[16384];   // [row 0..127][k' 0..63] bf16, 128 B rows
    __shared__ char Bs[16384];   // [d'  0..127][k' 0..63] bf16
    int tid = threadIdx.x;
    int n0 = blockIdx.x * 128;   // grid.x = 4
    int m0 = blockIdx.y * 128;   // grid.y = 784
    int lane = tid & 63, wv = tid >> 6;
    int wm = wv >> 1, wn = wv & 1;
    int ln = lane & 15, qd = lane >> 4;

    int bt_[4], hh_[4], ww_[4];
    const __hip_bfloat16* bptr[4];
    int rrow = tid >> 3, seg8 = (tid & 7) * 8;
    #pragma unroll
    for (int j = 0; j < 4; ++j) {
        int m = m0 + j * 32 + rrow;
        int bt = m / HW, q = m - bt * HW;
        bt_[j] = bt; hh_[j] = q / WW; ww_[j] = q - (q / WW) * WW;
        bptr[j] = wb + (size_t)(n0 + j * 32 + rrow) * 256 + seg8;
    }

    f32x4 acc[4][4];
    #pragma unroll
    for (int i = 0; i < 4; ++i)
        #pragma unroll
        for (int j = 0; j < 4; ++j) acc[i][j] = (f32x4){0.f, 0.f, 0.f, 0.f};

    for (int kk = 0; kk < 9; ++kk) {
        int kh = kk / 3, kw = kk - (kk / 3) * 3;
        const __hip_bfloat16* aptr[4];
        #pragma unroll
        for (int j = 0; j < 4; ++j)
            aptr[j] = xp + ((size_t)bt_[j] * 81 + (hh_[j] + kh) * 9 + (ww_[j] + kw)) * 256 + seg8;
        const size_t boff = (size_t)kk * (DD * 256);
        #pragma unroll
        for (int c0 = 0; c0 < 256; c0 += 64) {
            __syncthreads();
            #pragma unroll
            for (int j = 0; j < 4; ++j) {
                GLDS(aptr[j] + c0, As + j * 4096 + tid * 16);
                GLDS(bptr[j] + boff + c0, Bs + j * 4096 + tid * 16);
            }
            __syncthreads();
            #pragma unroll
            for (int k2 = 0; k2 < 2; ++k2) {
                bf16x8 af[4], bfr[4];
                #pragma unroll
                for (int i = 0; i < 4; ++i)
                    af[i] = *(const bf16x8*)(As + (wm * 64 + i * 16 + ln) * 128 + k2 * 64 + qd * 16);
                #pragma unroll
                for (int j = 0; j < 4; ++j)
                    bfr[j] = *(const bf16x8*)(Bs + (wn * 64 + j * 16 + ln) * 128 + k2 * 64 + qd * 16);
                #pragma unroll
                for (int i = 0; i < 4; ++i)
                    #pragma unroll
                    for (int j = 0; j < 4; ++j)
                        acc[i][j] = __builtin_amdgcn_mfma_f32_16x16x32_bf16(af[i], bfr[j], acc[i][j], 0, 0, 0);
            }
        }
    }

    float swr[4], cbr[4];
    #pragma unroll
    for (int j = 0; j < 4; ++j) {
        int n = n0 + wn * 64 + j * 16 + ln;
        swr[j] = scorew[n];
        cbr[j] = convb[n];
    }
    #pragma unroll
    for (int i = 0; i < 4; ++i) {
        #pragma unroll
        for (int r = 0; r < 4; ++r) {
            float v = 0.f;
            #pragma unroll
            for (int j = 0; j < 4; ++j) {
                float h1 = acc[i][j][r] + cbr[j];
                h1 = h1 > 0.f ? h1 : 0.f;
                v = fmaf(swr[j], h1, v);
            }
            v += __shfl_xor(v, 1);
            v += __shfl_xor(v, 2);
            v += __shfl_xor(v, 4);
            v += __shfl_xor(v, 8);
            if (ln == 0)
                atomicAdd(&logits[m0 + wm * 64 + i * 16 + qd * 4 + r], v);
        }
    }
}

// ---------------- K6: BCE per element + block partials ----------------------
__global__ void k_bce(const float* __restrict__ logits, const float* __restrict__ cam,
                      const float* __restrict__ sb, float* __restrict__ part) {
    __shared__ float sbuf[256];
    int tid = threadIdx.x;
    int m = blockIdx.x * 256 + tid;
    float l = logits[m] + sb[0];
    float y = cam[m];
    float v = fmaxf(l, 0.f) - l * y + log1pf(expf(-fabsf(l)));
    sbuf[tid] = v; __syncthreads();
    for (int k = 128; k > 0; k >>= 1) {
        if (tid < k) sbuf[tid] += sbuf[tid + k];
        __syncthreads();
    }
    if (tid == 0) part[blockIdx.x] = sbuf[0];
}

// ---------------- K7: final mean --------------------------------------------
__global__ void k_final(const float* __restrict__ part, float* __restrict__ out) {
    __shared__ float sbuf[256];
    int tid = threadIdx.x;
    float s = 0.f;
    for (int i = tid; i < 392; i += 256) s += part[i];
    sbuf[tid] = s; __syncthreads();
    for (int k = 128; k > 0; k >>= 1) {
        if (tid < k) sbuf[tid] += sbuf[tid + k];
        __syncthreads();
    }
    if (tid == 0) out[0] = sbuf[0] * (1.0f / (float)TOTAL);
}

extern "C" void kernel_launch(void* const* d_in, const int* in_sizes, int n_in,
                              void* d_out, int out_size, void* d_ws, size_t ws_size,
                              hipStream_t stream) {
    const float* x   = (const float*)d_in[0];
    const float* pv  = (const float*)d_in[1];
    const float* pn  = (const float*)d_in[2];
    const float* wpv = (const float*)d_in[3];
    const float* wpn = (const float*)d_in[4];
    const float* cw  = (const float*)d_in[5];
    const float* cb  = (const float*)d_in[6];
    const float* sw  = (const float*)d_in[7];
    const float* sb  = (const float*)d_in[8];

    char* w8 = (char*)d_ws;
    __hip_bfloat16* xp  = (__hip_bfloat16*)w8;                  // 84,934,656 B
    __hip_bfloat16* wb  = (__hip_bfloat16*)(w8 + 84934656);     //  2,359,296 B
    float* logits = (float*)(w8 + 87293952);                    //    401,408 B
    float* rowv   = (float*)(w8 + 87695360);
    float* rown_  = (float*)(w8 + 88096768);
    float* cam    = (float*)(w8 + 88498176);
    float* part   = (float*)(w8 + 88899584);                    //      1,568 B
    int*   clsv   = (int*)(w8 + 88901152);
    int*   clsn   = clsv + 64;

    k_argmax<<<1, 64, 0, stream>>>(pv, pn, clsv, clsn);
    k_xp<<<BB * TT, 256, 0, stream>>>(x, xp, wpv, wpn, clsv, clsn, rowv, rown_);
    k_wb<<<4608, 256, 0, stream>>>(cw, wb);
    k_cam<<<BB, 256, 0, stream>>>(rowv, rown_, cam);
    hipMemsetAsync(logits, 0, TOTAL * sizeof(float), stream);
    k_gemm<<<dim3(4, 784), 256, 0, stream>>>(xp, wb, cb, sw, logits);
    k_bce<<<392, 256, 0, stream>>>(logits, cam, sb, part);
    k_final<<<1, 256, 0, stream>>>(part, (float*)d_out);
}